// Round 1
// baseline (514.217 us; speedup 1.0000x reference)
//
#include <hip/hip_runtime.h>
#include <math.h>

#define T 8
#define N 2048
#define D 64
#define H 128
#define NH 4
#define HD 32
#define TE 16
#define OUT 64
#define E 80
#define MAXNB 2048

__device__ __forceinline__ float gelu_tanh(float x){
    float x3 = x*x*x;
    float t = tanhf(0.7978845608028654f*(x + 0.044715f*x3));
    return 0.5f*x*(1.0f+t);
}
__device__ __forceinline__ float sigmoidf_(float x){ return 1.0f/(1.0f+expf(-x)); }

// ---------------- K1: time-enhanced features + QKV projection (all t) --------
__global__ __launch_bounds__(256) void k_qkv(
    const float* __restrict__ nodes, const float* __restrict__ ts, const float* __restrict__ tf,
    const float* __restrict__ Wq, const float* __restrict__ bq,
    const float* __restrict__ Wk, const float* __restrict__ bk,
    const float* __restrict__ Wv, const float* __restrict__ bv,
    float* __restrict__ q, float* __restrict__ k, float* __restrict__ v)
{
    const int BR = 16;
    __shared__ float A[BR*E];
    int t  = blockIdx.x >> 7;            // 128 blocks per t
    int n0 = (blockIdx.x & 127) * BR;
    int tid = threadIdx.x;
    for (int idx = tid; idx < BR*E; idx += 256){
        int r = idx / E, e = idx - r*E;
        int n = n0 + r;
        float val;
        if (e < D) val = nodes[((size_t)(t*N+n))*D + e];
        else {
            int j = (e - D) & 7;
            float ang = ts[t*N+n] * tf[t*(TE/2)+j];
            val = (e < D+8) ? sinf(ang) : cosf(ang);
        }
        A[idx] = val;
    }
    __syncthreads();
    for (int jj = tid; jj < 3*H; jj += 256){
        int sel = jj >> 7, j = jj & 127;
        const float* W = (sel==0?Wq:(sel==1?Wk:Wv)) + (size_t)t*E*H;
        const float* B = (sel==0?bq:(sel==1?bk:bv)) + t*H;
        float acc[BR];
        float bias = B[j];
        #pragma unroll
        for (int r=0;r<BR;r++) acc[r]=bias;
        for (int e=0;e<E;e+=4){
            float w0=W[(e+0)*H+j], w1=W[(e+1)*H+j], w2=W[(e+2)*H+j], w3=W[(e+3)*H+j];
            #pragma unroll
            for (int r=0;r<BR;r++){
                float4 a = *(const float4*)&A[r*E+e];
                acc[r] += a.x*w0 + a.y*w1 + a.z*w2 + a.w*w3;
            }
        }
        float* outp = (sel==0?q:(sel==1?k:v));
        #pragma unroll
        for (int r=0;r<BR;r++) outp[((size_t)(t*N+n0+r))*H + j] = acc[r];
    }
}

// ---------------- K2: sparse masked attention + LayerNorm (one row per block) -
__global__ __launch_bounds__(256) void k_attn(
    const float* __restrict__ adj, const float* __restrict__ ts,
    const float* __restrict__ q, const float* __restrict__ k, const float* __restrict__ v,
    const float* __restrict__ ln_g, const float* __restrict__ ln_b,
    float* __restrict__ mhn)
{
    __shared__ unsigned short nb[MAXNB];
    __shared__ float sc[MAXNB*NH];   // 32 KB
    __shared__ float qrow[H];
    __shared__ float mh[H];
    __shared__ int wcnt[4], wbase[4];
    __shared__ int cnt_s;
    __shared__ float red[2];

    int t = blockIdx.x >> 11;        // 2048 rows per t
    int n = blockIdx.x & 2047;
    int tid = threadIdx.x;
    int wid = tid >> 6, lane = tid & 63;
    size_t rowbase = (size_t)(t*N+n);
    const float* arow = adj + rowbase * (size_t)N;
    float tsn = ts[t*N+n];
    if (tid == 0) cnt_s = 0;
    if (tid < H) qrow[tid] = q[rowbase*H + tid];
    __syncthreads();

    // deterministic neighbor compaction (sorted by m)
    for (int base = 0; base < N; base += 256){
        int m = base + tid;
        bool f = (arow[m] > 0.0f) || (m == n);
        unsigned long long msk = __ballot(f);
        if (lane == 0) wcnt[wid] = __popcll(msk);
        __syncthreads();
        if (tid == 0){
            int s = cnt_s;
            for (int w2=0; w2<4; w2++){ wbase[w2]=s; s+=wcnt[w2]; }
            cnt_s = s;
        }
        __syncthreads();
        if (f){
            int pos = wbase[wid] + __popcll(msk & ((1ull<<lane)-1ull));
            nb[pos] = (unsigned short)m;
        }
        __syncthreads();
    }
    int cnt = cnt_s;

    // scores for (neighbor, head) pairs
    const float inv_sqrt_hd = 0.17677669529663687f;
    for (int i = tid; i < cnt*NH; i += 256){
        int m  = nb[i >> 2];
        int hh = i & 3;
        const float4* kp = (const float4*)(k + ((size_t)(t*N+m))*H + hh*HD);
        const float4* qp = (const float4*)(qrow + hh*HD);
        float dot = 0.f;
        #pragma unroll
        for (int u=0; u<HD/4; u++){
            float4 a = qp[u], b = kp[u];
            dot += a.x*b.x + a.y*b.y + a.z*b.z + a.w*b.w;
        }
        float dt = fabsf(tsn - ts[t*N+m]);
        sc[i] = dot * inv_sqrt_hd * expf(-dt * 0.1f);
    }
    __syncthreads();

    // per-head softmax + weighted V (wave wid owns head wid)
    {
        int hh = wid;
        float mx = -3.402823466e38f;
        for (int i = lane; i < cnt; i += 64) mx = fmaxf(mx, sc[i*NH+hh]);
        #pragma unroll
        for (int off=32; off; off>>=1) mx = fmaxf(mx, __shfl_xor(mx, off));
        float sum = 0.f;
        for (int i = lane; i < cnt; i += 64){
            float p = expf(sc[i*NH+hh] - mx);
            sc[i*NH+hh] = p;
            sum += p;
        }
        #pragma unroll
        for (int off=32; off; off>>=1) sum += __shfl_xor(sum, off);
        __syncthreads();
        int d = lane & 31, half = lane >> 5;
        float acc = 0.f;
        for (int i = half; i < cnt; i += 2){
            int m = nb[i];
            acc += sc[i*NH+hh] * v[((size_t)(t*N+m))*H + hh*HD + d];
        }
        acc += __shfl_xor(acc, 32);
        if (half == 0) mh[hh*HD + d] = acc / sum;
    }
    __syncthreads();

    // fused LayerNorm (eps=1e-6)
    if (wid == 0){
        float s = mh[lane] + mh[lane+64];
        #pragma unroll
        for (int off=32; off; off>>=1) s += __shfl_xor(s, off);
        float mu = s * (1.0f/H);
        float d0 = mh[lane]-mu, d1 = mh[lane+64]-mu;
        float vv = d0*d0 + d1*d1;
        #pragma unroll
        for (int off=32; off; off>>=1) vv += __shfl_xor(vv, off);
        if (lane == 0){ red[0] = mu; red[1] = vv*(1.0f/H); }
    }
    __syncthreads();
    if (tid < H){
        float mu = red[0];
        float rs = rsqrtf(red[1] + 1e-6f);
        mhn[rowbase*H + tid] = (mh[tid]-mu)*rs*ln_g[t*H+tid] + ln_b[t*H+tid];
    }
}

// ---------------- K3: GELU-MLP 128 -> 256 -> 128 (all t) ---------------------
__global__ __launch_bounds__(256) void k_ff(
    const float* __restrict__ mhn,
    const float* __restrict__ W1, const float* __restrict__ b1,
    const float* __restrict__ W2, const float* __restrict__ b2,
    float* __restrict__ ff)
{
    const int BR = 16;
    __shared__ float A[BR*H];
    __shared__ float U[BR*2*H];
    int t  = blockIdx.x >> 7;
    int n0 = (blockIdx.x & 127) * BR;
    int tid = threadIdx.x;
    for (int idx = tid; idx < BR*H; idx += 256)
        A[idx] = mhn[((size_t)(t*N+n0))*H + idx];
    __syncthreads();
    {
        int j = tid;
        const float* W = W1 + (size_t)t*H*2*H;
        float acc[BR];
        float bias = b1[t*2*H + j];
        #pragma unroll
        for (int r=0;r<BR;r++) acc[r]=bias;
        for (int e=0;e<H;e+=4){
            float w0=W[(e+0)*256+j],w1=W[(e+1)*256+j],w2=W[(e+2)*256+j],w3=W[(e+3)*256+j];
            #pragma unroll
            for (int r=0;r<BR;r++){
                float4 a = *(const float4*)&A[r*H+e];
                acc[r] += a.x*w0+a.y*w1+a.z*w2+a.w*w3;
            }
        }
        #pragma unroll
        for (int r=0;r<BR;r++) U[r*256+j] = gelu_tanh(acc[r]);
    }
    __syncthreads();
    {
        int j = tid & 127, rg = tid >> 7;   // 2 groups x 8 rows
        const float* W = W2 + (size_t)t*2*H*H;
        float acc[8];
        float bias = b2[t*H+j];
        #pragma unroll
        for (int rr=0;rr<8;rr++) acc[rr]=bias;
        for (int e=0;e<256;e+=4){
            float w0=W[(e+0)*H+j],w1=W[(e+1)*H+j],w2=W[(e+2)*H+j],w3=W[(e+3)*H+j];
            #pragma unroll
            for (int rr=0;rr<8;rr++){
                int r = rg*8+rr;
                float4 a = *(const float4*)&U[r*256+e];
                acc[rr] += a.x*w0+a.y*w1+a.z*w2+a.w*w3;
            }
        }
        #pragma unroll
        for (int rr=0;rr<8;rr++) ff[((size_t)(t*N+n0+rg*8+rr))*H + j] = acc[rr];
    }
}

// ---------------- K4: GRU bottom-half projections ff@W_bot + b (all t) -------
__global__ __launch_bounds__(256) void k_gru_pre(
    const float* __restrict__ ff,
    const float* __restrict__ Wr, const float* __restrict__ br,
    const float* __restrict__ Wz, const float* __restrict__ bz,
    const float* __restrict__ Wn, const float* __restrict__ bn,
    float* __restrict__ fr, float* __restrict__ fz, float* __restrict__ fn)
{
    const int BR = 16;
    __shared__ float A[BR*H];
    int t  = blockIdx.x >> 7;
    int n0 = (blockIdx.x & 127) * BR;
    int tid = threadIdx.x;
    for (int idx = tid; idx < BR*H; idx += 256)
        A[idx] = ff[((size_t)(t*N+n0))*H + idx];
    __syncthreads();
    for (int jj = tid; jj < 3*H; jj += 256){
        int sel = jj >> 7, j = jj & 127;
        const float* W = (sel==0?Wr:(sel==1?Wz:Wn)) + (size_t)t*2*H*H + (size_t)H*H; // bottom rows 128..255
        const float* B = (sel==0?br:(sel==1?bz:bn)) + t*H;
        float* outp = (sel==0?fr:(sel==1?fz:fn));
        float acc[BR];
        float bias = B[j];
        #pragma unroll
        for (int r=0;r<BR;r++) acc[r]=bias;
        for (int e=0;e<H;e+=4){
            float w0=W[(e+0)*H+j],w1=W[(e+1)*H+j],w2=W[(e+2)*H+j],w3=W[(e+3)*H+j];
            #pragma unroll
            for (int r=0;r<BR;r++){
                float4 a = *(const float4*)&A[r*H+e];
                acc[r]+=a.x*w0+a.y*w1+a.z*w2+a.w*w3;
            }
        }
        #pragma unroll
        for (int r=0;r<BR;r++) outp[((size_t)(t*N+n0+r))*H + j] = acc[r];
    }
}

// ---------------- K5: GRU sequential step (in-place h update) ----------------
__global__ __launch_bounds__(256) void k_gru_step(
    float* h,
    const float* __restrict__ fr, const float* __restrict__ fz, const float* __restrict__ fn,
    const float* __restrict__ Wr, const float* __restrict__ Wz, const float* __restrict__ Wn,
    int t)
{
    const int BR = 8;
    __shared__ float Hs[BR*H], Rl[BR*H], Zl[BR*H], RH[BR*H];
    int n0 = blockIdx.x * BR;
    int tid = threadIdx.x;
    for (int idx = tid; idx < BR*H; idx += 256)
        Hs[idx] = h[(size_t)n0*H + idx];
    __syncthreads();
    {
        int sel = tid >> 7, j = tid & 127;
        const float* W = (sel==0?Wr:Wz) + (size_t)t*2*H*H;   // top rows 0..127
        const float* P = (sel==0?fr:fz);
        float acc[BR];
        #pragma unroll
        for (int r=0;r<BR;r++) acc[r] = P[((size_t)(t*N+n0+r))*H + j];
        for (int e=0;e<H;e+=4){
            float w0=W[(e+0)*H+j],w1=W[(e+1)*H+j],w2=W[(e+2)*H+j],w3=W[(e+3)*H+j];
            #pragma unroll
            for (int r=0;r<BR;r++){
                float4 a = *(const float4*)&Hs[r*H+e];
                acc[r]+=a.x*w0+a.y*w1+a.z*w2+a.w*w3;
            }
        }
        float* Dst = (sel==0?Rl:Zl);
        #pragma unroll
        for (int r=0;r<BR;r++) Dst[r*H+j] = sigmoidf_(acc[r]);
    }
    __syncthreads();
    for (int idx = tid; idx < BR*H; idx += 256) RH[idx] = Rl[idx]*Hs[idx];
    __syncthreads();
    {
        int rg = tid >> 7, j = tid & 127;   // rows rg*4 .. rg*4+3
        const float* W = Wn + (size_t)t*2*H*H;
        float acc[4];
        #pragma unroll
        for (int rr=0;rr<4;rr++) acc[rr] = fn[((size_t)(t*N+n0+rg*4+rr))*H + j];
        for (int e=0;e<H;e+=4){
            float w0=W[(e+0)*H+j],w1=W[(e+1)*H+j],w2=W[(e+2)*H+j],w3=W[(e+3)*H+j];
            #pragma unroll
            for (int rr=0;rr<4;rr++){
                int r = rg*4+rr;
                float4 a = *(const float4*)&RH[r*H+e];
                acc[rr]+=a.x*w0+a.y*w1+a.z*w2+a.w*w3;
            }
        }
        #pragma unroll
        for (int rr=0;rr<4;rr++){
            int r = rg*4+rr;
            float nv = tanhf(acc[rr]);
            float zz = Zl[r*H+j];
            h[(size_t)(n0+r)*H + j] = (1.f-zz)*nv + zz*Hs[r*H+j];
        }
    }
}

// ---------------- K6: final projection h @ Wout + bout ----------------------
__global__ __launch_bounds__(256) void k_out(
    const float* __restrict__ h, const float* __restrict__ Wout, const float* __restrict__ bout,
    float* __restrict__ out)
{
    const int BR = 16;
    __shared__ float Hs[BR*H];
    int n0 = blockIdx.x * BR;
    int tid = threadIdx.x;
    for (int idx=tid; idx<BR*H; idx+=256) Hs[idx] = h[(size_t)n0*H+idx];
    __syncthreads();
    int j = tid & 63, rg = tid >> 6;   // 4 groups x 4 rows
    float acc[4];
    float bias = bout[j];
    #pragma unroll
    for (int rr=0;rr<4;rr++) acc[rr]=bias;
    for (int e=0;e<H;e+=4){
        float w0=Wout[(e+0)*OUT+j],w1=Wout[(e+1)*OUT+j],w2=Wout[(e+2)*OUT+j],w3=Wout[(e+3)*OUT+j];
        #pragma unroll
        for (int rr=0;rr<4;rr++){
            int r = rg*4+rr;
            float4 a = *(const float4*)&Hs[r*H+e];
            acc[rr]+=a.x*w0+a.y*w1+a.z*w2+a.w*w3;
        }
    }
    #pragma unroll
    for (int rr=0;rr<4;rr++) out[(size_t)(n0+rg*4+rr)*OUT + j] = acc[rr];
}

extern "C" void kernel_launch(void* const* d_in, const int* in_sizes, int n_in,
                              void* d_out, int out_size, void* d_ws, size_t ws_size,
                              hipStream_t stream)
{
    const float* nodes = (const float*)d_in[0];
    const float* adj   = (const float*)d_in[1];
    const float* ts    = (const float*)d_in[2];
    // d_in[3] = edge_sequence (unused by the math)
    const float* tf    = (const float*)d_in[4];
    const float* Wq = (const float*)d_in[5];  const float* bq = (const float*)d_in[6];
    const float* Wk = (const float*)d_in[7];  const float* bk = (const float*)d_in[8];
    const float* Wv = (const float*)d_in[9];  const float* bv = (const float*)d_in[10];
    const float* lng = (const float*)d_in[11]; const float* lnb = (const float*)d_in[12];
    const float* W1 = (const float*)d_in[13]; const float* b1 = (const float*)d_in[14];
    const float* W2 = (const float*)d_in[15]; const float* b2 = (const float*)d_in[16];
    const float* Wr = (const float*)d_in[17]; const float* br = (const float*)d_in[18];
    const float* Wz = (const float*)d_in[19]; const float* bz = (const float*)d_in[20];
    const float* Wn = (const float*)d_in[21]; const float* bn = (const float*)d_in[22];
    const float* Wout = (const float*)d_in[23]; const float* bout = (const float*)d_in[24];
    float* out = (float*)d_out;

    const size_t TNH = (size_t)T*N*H;
    float* ws  = (float*)d_ws;
    float* q   = ws;
    float* k   = q  + TNH;
    float* v   = k  + TNH;
    float* mhn = v  + TNH;
    float* ff  = mhn+ TNH;
    float* fr  = ff + TNH;
    float* fz  = fr + TNH;
    float* fn  = fz + TNH;
    float* h   = fn + TNH;     // N*H

    k_qkv<<<dim3(T*(N/16)), dim3(256), 0, stream>>>(nodes, ts, tf, Wq,bq, Wk,bk, Wv,bv, q,k,v);
    k_attn<<<dim3(T*N), dim3(256), 0, stream>>>(adj, ts, q,k,v, lng,lnb, mhn);
    k_ff<<<dim3(T*(N/16)), dim3(256), 0, stream>>>(mhn, W1,b1, W2,b2, ff);
    k_gru_pre<<<dim3(T*(N/16)), dim3(256), 0, stream>>>(ff, Wr,br, Wz,bz, Wn,bn, fr,fz,fn);
    hipMemsetAsync(h, 0, (size_t)N*H*sizeof(float), stream);
    for (int t=0; t<T; t++)
        k_gru_step<<<dim3(N/8), dim3(256), 0, stream>>>(h, fr,fz,fn, Wr,Wz,Wn, t);
    k_out<<<dim3(N/16), dim3(256), 0, stream>>>(h, Wout, bout, out);
}

// Round 2
// 375.285 us; speedup vs baseline: 1.3702x; 1.3702x over previous
//
#include <hip/hip_runtime.h>
#include <math.h>

#define T 8
#define N 2048
#define D 64
#define H 128
#define NH 4
#define HD 32
#define TE 16
#define OUT 64
#define E 80
#define CH 128   // score-chunk (online softmax bounds LDS for pathological rows)

__device__ __forceinline__ float gelu_tanh(float x){
    float x3 = x*x*x;
    float t = tanhf(0.7978845608028654f*(x + 0.044715f*x3));
    return 0.5f*x*(1.0f+t);
}
__device__ __forceinline__ float sigmoidf_(float x){ return 1.0f/(1.0f+expf(-x)); }

// ---------------- K1: time-enhanced features + QKV projection (all t) --------
__global__ __launch_bounds__(256) void k_qkv(
    const float* __restrict__ nodes, const float* __restrict__ ts, const float* __restrict__ tf,
    const float* __restrict__ Wq, const float* __restrict__ bq,
    const float* __restrict__ Wk, const float* __restrict__ bk,
    const float* __restrict__ Wv, const float* __restrict__ bv,
    float* __restrict__ q, float* __restrict__ k, float* __restrict__ v)
{
    const int BR = 16;
    __shared__ float A[BR*E];
    int t  = blockIdx.x >> 7;            // 128 blocks per t
    int n0 = (blockIdx.x & 127) * BR;
    int tid = threadIdx.x;
    for (int idx = tid; idx < BR*E; idx += 256){
        int r = idx / E, e = idx - r*E;
        int n = n0 + r;
        float val;
        if (e < D) val = nodes[((size_t)(t*N+n))*D + e];
        else {
            int j = (e - D) & 7;
            float ang = ts[t*N+n] * tf[t*(TE/2)+j];
            val = (e < D+8) ? sinf(ang) : cosf(ang);
        }
        A[idx] = val;
    }
    __syncthreads();
    for (int jj = tid; jj < 3*H; jj += 256){
        int sel = jj >> 7, j = jj & 127;
        const float* W = (sel==0?Wq:(sel==1?Wk:Wv)) + (size_t)t*E*H;
        const float* B = (sel==0?bq:(sel==1?bk:bv)) + t*H;
        float acc[BR];
        float bias = B[j];
        #pragma unroll
        for (int r=0;r<BR;r++) acc[r]=bias;
        for (int e=0;e<E;e+=4){
            float w0=W[(e+0)*H+j], w1=W[(e+1)*H+j], w2=W[(e+2)*H+j], w3=W[(e+3)*H+j];
            #pragma unroll
            for (int r=0;r<BR;r++){
                float4 a = *(const float4*)&A[r*E+e];
                acc[r] += a.x*w0 + a.y*w1 + a.z*w2 + a.w*w3;
            }
        }
        float* outp = (sel==0?q:(sel==1?k:v));
        #pragma unroll
        for (int r=0;r<BR;r++) outp[((size_t)(t*N+n0+r))*H + j] = acc[r];
    }
}

// ---------------- K2: sparse masked attention + LayerNorm --------------------
// One WAVE per row (4 rows/block), no block barriers, wave-local ballot
// compaction, 16-lane-per-head softmax, online rescale across CH chunks.
__global__ __launch_bounds__(256) void k_attn(
    const float* __restrict__ adj, const float* __restrict__ ts,
    const float* __restrict__ q, const float* __restrict__ k, const float* __restrict__ v,
    const float* __restrict__ ln_g, const float* __restrict__ ln_b,
    float* __restrict__ mhn)
{
    __shared__ unsigned short nb_s[4][N];     // 16 KB
    __shared__ float sc_s[4][CH][NH];         // 8 KB
    __shared__ float qrow_s[4][H];            // 2 KB

    int wid  = threadIdx.x >> 6;
    int lane = threadIdx.x & 63;
    int row  = blockIdx.x*4 + wid;            // 0 .. T*N-1
    int t = row >> 11, n = row & 2047;
    size_t rowbase = (size_t)row;
    const float4* arow4 = (const float4*)(adj + rowbase*(size_t)N);
    float tsn = ts[row];

    qrow_s[wid][lane]    = q[rowbase*H + lane];
    qrow_s[wid][lane+64] = q[rowbase*H + lane + 64];
    __builtin_amdgcn_wave_barrier();

    // ---- wave-local neighbor compaction (ordered, deterministic) ----
    int cnt = 0;
    unsigned long long lt = (1ull<<lane)-1ull;
    for (int base = 0; base < N; base += 256){
        float4 a4 = arow4[(base>>2)+lane];
        int m0 = base + lane*4;
        bool f0 = (a4.x>0.f) || (m0   == n);
        bool f1 = (a4.y>0.f) || (m0+1 == n);
        bool f2 = (a4.z>0.f) || (m0+2 == n);
        bool f3 = (a4.w>0.f) || (m0+3 == n);
        unsigned long long b0=__ballot(f0), b1=__ballot(f1), b2=__ballot(f2), b3=__ballot(f3);
        int before = __popcll(b0&lt)+__popcll(b1&lt)+__popcll(b2&lt)+__popcll(b3&lt);
        int pos = cnt + before;
        if (f0) nb_s[wid][pos] = (unsigned short)(m0  );  pos += f0;
        if (f1) nb_s[wid][pos] = (unsigned short)(m0+1);  pos += f1;
        if (f2) nb_s[wid][pos] = (unsigned short)(m0+2);  pos += f2;
        if (f3) nb_s[wid][pos] = (unsigned short)(m0+3);  pos += f3;
        cnt += __popcll(b0)+__popcll(b1)+__popcll(b2)+__popcll(b3);
    }
    __builtin_amdgcn_wave_barrier();

    // ---- online softmax + PV over chunks ----
    const float inv_sqrt_hd = 0.17677669529663687f;
    int hh16 = lane >> 4;          // head this lane serves in softmax (16 lanes/head)
    int l16  = lane & 15;
    int ha0  = lane >> 5;          // head of output dim j0=lane     (0/1)
    int ha1  = ha0 + 2;            // head of output dim j1=lane+64  (2/3)
    float m_run = -3.402823466e38f, s_run = 0.f;
    float acc0 = 0.f, acc1 = 0.f;

    for (int cb = 0; cb < cnt; cb += CH){
        int cc = min(CH, cnt - cb);
        // scores for (neighbor, head)
        for (int i = lane; i < cc*NH; i += 64){
            int li = i >> 2, hh = i & 3;
            int m = nb_s[wid][cb + li];
            const float4* kp = (const float4*)(k + ((size_t)t*N + m)*H + hh*HD);
            const float4* qp = (const float4*)&qrow_s[wid][hh*HD];
            float dot = 0.f;
            #pragma unroll
            for (int u=0;u<8;u++){
                float4 a = qp[u], b = kp[u];
                dot += a.x*b.x + a.y*b.y + a.z*b.z + a.w*b.w;
            }
            float dt = fabsf(tsn - ts[t*N + m]);
            sc_s[wid][li][hh] = dot * inv_sqrt_hd * expf(-dt*0.1f);
        }
        __builtin_amdgcn_wave_barrier();
        // chunk max per head
        float mx = -3.402823466e38f;
        for (int i = l16; i < cc; i += 16) mx = fmaxf(mx, sc_s[wid][i][hh16]);
        #pragma unroll
        for (int off=8; off; off>>=1) mx = fmaxf(mx, __shfl_xor(mx, off, 16));
        float m_new = fmaxf(m_run, mx);
        float scale = expf(m_run - m_new);     // first chunk: exp(-inf)=0
        float sum = 0.f;
        for (int i = l16; i < cc; i += 16){
            float p = expf(sc_s[wid][i][hh16] - m_new);
            sc_s[wid][i][hh16] = p;
            sum += p;
        }
        #pragma unroll
        for (int off=8; off; off>>=1) sum += __shfl_xor(sum, off, 16);
        s_run = s_run*scale + sum;
        m_run = m_new;
        float sca0 = __shfl(scale, ha0*16, 64);
        float sca1 = __shfl(scale, ha1*16, 64);
        acc0 *= sca0; acc1 *= sca1;
        __builtin_amdgcn_wave_barrier();
        // PV: lane accumulates output dims (lane) and (lane+64)
        for (int i = 0; i < cc; i++){
            int m = nb_s[wid][cb + i];
            const float* vp = v + ((size_t)t*N + m)*H;
            float p0 = sc_s[wid][i][ha0];
            float p1 = sc_s[wid][i][ha1];
            acc0 += p0 * vp[lane];
            acc1 += p1 * vp[lane+64];
        }
        __builtin_amdgcn_wave_barrier();
    }

    float s0 = __shfl(s_run, ha0*16, 64);
    float s1 = __shfl(s_run, ha1*16, 64);
    float mh0 = acc0 / s0, mh1 = acc1 / s1;

    // fused LayerNorm (eps=1e-6), all in-wave
    float sum = mh0 + mh1;
    #pragma unroll
    for (int off=32; off; off>>=1) sum += __shfl_xor(sum, off);
    float mu = sum * (1.f/128.f);
    float d0 = mh0 - mu, d1 = mh1 - mu;
    float vv = d0*d0 + d1*d1;
    #pragma unroll
    for (int off=32; off; off>>=1) vv += __shfl_xor(vv, off);
    float rs = rsqrtf(vv*(1.f/128.f) + 1e-6f);
    mhn[rowbase*H + lane]      = d0*rs*ln_g[t*H+lane]      + ln_b[t*H+lane];
    mhn[rowbase*H + lane+64]   = d1*rs*ln_g[t*H+lane+64]   + ln_b[t*H+lane+64];
}

// ---------------- K3: GELU-MLP 128 -> 256 -> 128 (all t) ---------------------
__global__ __launch_bounds__(256) void k_ff(
    const float* __restrict__ mhn,
    const float* __restrict__ W1, const float* __restrict__ b1,
    const float* __restrict__ W2, const float* __restrict__ b2,
    float* __restrict__ ff)
{
    const int BR = 16;
    __shared__ float A[BR*H];
    __shared__ float U[BR*2*H];
    int t  = blockIdx.x >> 7;
    int n0 = (blockIdx.x & 127) * BR;
    int tid = threadIdx.x;
    for (int idx = tid; idx < BR*H; idx += 256)
        A[idx] = mhn[((size_t)(t*N+n0))*H + idx];
    __syncthreads();
    {
        int j = tid;
        const float* W = W1 + (size_t)t*H*2*H;
        float acc[BR];
        float bias = b1[t*2*H + j];
        #pragma unroll
        for (int r=0;r<BR;r++) acc[r]=bias;
        for (int e=0;e<H;e+=4){
            float w0=W[(e+0)*256+j],w1=W[(e+1)*256+j],w2=W[(e+2)*256+j],w3=W[(e+3)*256+j];
            #pragma unroll
            for (int r=0;r<BR;r++){
                float4 a = *(const float4*)&A[r*H+e];
                acc[r] += a.x*w0+a.y*w1+a.z*w2+a.w*w3;
            }
        }
        #pragma unroll
        for (int r=0;r<BR;r++) U[r*256+j] = gelu_tanh(acc[r]);
    }
    __syncthreads();
    {
        int j = tid & 127, rg = tid >> 7;   // 2 groups x 8 rows
        const float* W = W2 + (size_t)t*2*H*H;
        float acc[8];
        float bias = b2[t*H+j];
        #pragma unroll
        for (int rr=0;rr<8;rr++) acc[rr]=bias;
        for (int e=0;e<256;e+=4){
            float w0=W[(e+0)*H+j],w1=W[(e+1)*H+j],w2=W[(e+2)*H+j],w3=W[(e+3)*H+j];
            #pragma unroll
            for (int rr=0;rr<8;rr++){
                int r = rg*8+rr;
                float4 a = *(const float4*)&U[r*256+e];
                acc[rr] += a.x*w0+a.y*w1+a.z*w2+a.w*w3;
            }
        }
        #pragma unroll
        for (int rr=0;rr<8;rr++) ff[((size_t)(t*N+n0+rg*8+rr))*H + j] = acc[rr];
    }
}

// ---------------- K4: GRU bottom-half projections ff@W_bot + b (all t) -------
__global__ __launch_bounds__(256) void k_gru_pre(
    const float* __restrict__ ff,
    const float* __restrict__ Wr, const float* __restrict__ br,
    const float* __restrict__ Wz, const float* __restrict__ bz,
    const float* __restrict__ Wn, const float* __restrict__ bn,
    float* __restrict__ fr, float* __restrict__ fz, float* __restrict__ fn)
{
    const int BR = 16;
    __shared__ float A[BR*H];
    int t  = blockIdx.x >> 7;
    int n0 = (blockIdx.x & 127) * BR;
    int tid = threadIdx.x;
    for (int idx = tid; idx < BR*H; idx += 256)
        A[idx] = ff[((size_t)(t*N+n0))*H + idx];
    __syncthreads();
    for (int jj = tid; jj < 3*H; jj += 256){
        int sel = jj >> 7, j = jj & 127;
        const float* W = (sel==0?Wr:(sel==1?Wz:Wn)) + (size_t)t*2*H*H + (size_t)H*H; // bottom rows
        const float* B = (sel==0?br:(sel==1?bz:bn)) + t*H;
        float* outp = (sel==0?fr:(sel==1?fz:fn));
        float acc[BR];
        float bias = B[j];
        #pragma unroll
        for (int r=0;r<BR;r++) acc[r]=bias;
        for (int e=0;e<H;e+=4){
            float w0=W[(e+0)*H+j],w1=W[(e+1)*H+j],w2=W[(e+2)*H+j],w3=W[(e+3)*H+j];
            #pragma unroll
            for (int r=0;r<BR;r++){
                float4 a = *(const float4*)&A[r*H+e];
                acc[r]+=a.x*w0+a.y*w1+a.z*w2+a.w*w3;
            }
        }
        #pragma unroll
        for (int r=0;r<BR;r++) outp[((size_t)(t*N+n0+r))*H + j] = acc[r];
    }
}

// ---------------- K5: GRU sequential step (in-place h update) ----------------
__global__ __launch_bounds__(256) void k_gru_step(
    float* h,
    const float* __restrict__ fr, const float* __restrict__ fz, const float* __restrict__ fn,
    const float* __restrict__ Wr, const float* __restrict__ Wz, const float* __restrict__ Wn,
    int t)
{
    const int BR = 8;
    __shared__ float Hs[BR*H], Rl[BR*H], Zl[BR*H], RH[BR*H];
    int n0 = blockIdx.x * BR;
    int tid = threadIdx.x;
    for (int idx = tid; idx < BR*H; idx += 256)
        Hs[idx] = h[(size_t)n0*H + idx];
    __syncthreads();
    {
        int sel = tid >> 7, j = tid & 127;
        const float* W = (sel==0?Wr:Wz) + (size_t)t*2*H*H;   // top rows 0..127
        const float* P = (sel==0?fr:fz);
        float acc[BR];
        #pragma unroll
        for (int r=0;r<BR;r++) acc[r] = P[((size_t)(t*N+n0+r))*H + j];
        for (int e=0;e<H;e+=4){
            float w0=W[(e+0)*H+j],w1=W[(e+1)*H+j],w2=W[(e+2)*H+j],w3=W[(e+3)*H+j];
            #pragma unroll
            for (int r=0;r<BR;r++){
                float4 a = *(const float4*)&Hs[r*H+e];
                acc[r]+=a.x*w0+a.y*w1+a.z*w2+a.w*w3;
            }
        }
        float* Dst = (sel==0?Rl:Zl);
        #pragma unroll
        for (int r=0;r<BR;r++) Dst[r*H+j] = sigmoidf_(acc[r]);
    }
    __syncthreads();
    for (int idx = tid; idx < BR*H; idx += 256) RH[idx] = Rl[idx]*Hs[idx];
    __syncthreads();
    {
        int rg = tid >> 7, j = tid & 127;
        const float* W = Wn + (size_t)t*2*H*H;
        float acc[4];
        #pragma unroll
        for (int rr=0;rr<4;rr++) acc[rr] = fn[((size_t)(t*N+n0+rg*4+rr))*H + j];
        for (int e=0;e<H;e+=4){
            float w0=W[(e+0)*H+j],w1=W[(e+1)*H+j],w2=W[(e+2)*H+j],w3=W[(e+3)*H+j];
            #pragma unroll
            for (int rr=0;rr<4;rr++){
                int r = rg*4+rr;
                float4 a = *(const float4*)&RH[r*H+e];
                acc[rr]+=a.x*w0+a.y*w1+a.z*w2+a.w*w3;
            }
        }
        #pragma unroll
        for (int rr=0;rr<4;rr++){
            int r = rg*4+rr;
            float nv = tanhf(acc[rr]);
            float zz = Zl[r*H+j];
            h[(size_t)(n0+r)*H + j] = (1.f-zz)*nv + zz*Hs[r*H+j];
        }
    }
}

// ---------------- K6: final projection h @ Wout + bout ----------------------
__global__ __launch_bounds__(256) void k_out(
    const float* __restrict__ h, const float* __restrict__ Wout, const float* __restrict__ bout,
    float* __restrict__ out)
{
    const int BR = 16;
    __shared__ float Hs[BR*H];
    int n0 = blockIdx.x * BR;
    int tid = threadIdx.x;
    for (int idx=tid; idx<BR*H; idx+=256) Hs[idx] = h[(size_t)n0*H+idx];
    __syncthreads();
    int j = tid & 63, rg = tid >> 6;
    float acc[4];
    float bias = bout[j];
    #pragma unroll
    for (int rr=0;rr<4;rr++) acc[rr]=bias;
    for (int e=0;e<H;e+=4){
        float w0=Wout[(e+0)*OUT+j],w1=Wout[(e+1)*OUT+j],w2=Wout[(e+2)*OUT+j],w3=Wout[(e+3)*OUT+j];
        #pragma unroll
        for (int rr=0;rr<4;rr++){
            int r = rg*4+rr;
            float4 a = *(const float4*)&Hs[r*H+e];
            acc[rr]+=a.x*w0+a.y*w1+a.z*w2+a.w*w3;
        }
    }
    #pragma unroll
    for (int rr=0;rr<4;rr++) out[(size_t)(n0+rg*4+rr)*OUT + j] = acc[rr];
}

extern "C" void kernel_launch(void* const* d_in, const int* in_sizes, int n_in,
                              void* d_out, int out_size, void* d_ws, size_t ws_size,
                              hipStream_t stream)
{
    const float* nodes = (const float*)d_in[0];
    const float* adj   = (const float*)d_in[1];
    const float* ts    = (const float*)d_in[2];
    // d_in[3] = edge_sequence (unused)
    const float* tf    = (const float*)d_in[4];
    const float* Wq = (const float*)d_in[5];  const float* bq = (const float*)d_in[6];
    const float* Wk = (const float*)d_in[7];  const float* bk = (const float*)d_in[8];
    const float* Wv = (const float*)d_in[9];  const float* bv = (const float*)d_in[10];
    const float* lng = (const float*)d_in[11]; const float* lnb = (const float*)d_in[12];
    const float* W1 = (const float*)d_in[13]; const float* b1 = (const float*)d_in[14];
    const float* W2 = (const float*)d_in[15]; const float* b2 = (const float*)d_in[16];
    const float* Wr = (const float*)d_in[17]; const float* br = (const float*)d_in[18];
    const float* Wz = (const float*)d_in[19]; const float* bz = (const float*)d_in[20];
    const float* Wn = (const float*)d_in[21]; const float* bn = (const float*)d_in[22];
    const float* Wout = (const float*)d_in[23]; const float* bout = (const float*)d_in[24];
    float* out = (float*)d_out;

    const size_t TNH = (size_t)T*N*H;
    float* ws  = (float*)d_ws;
    float* q   = ws;
    float* k   = q  + TNH;
    float* v   = k  + TNH;
    float* mhn = v  + TNH;
    float* ff  = mhn+ TNH;
    float* fr  = ff + TNH;
    float* fz  = fr + TNH;
    float* fn  = fz + TNH;
    float* h   = fn + TNH;     // N*H

    k_qkv<<<dim3(T*(N/16)), dim3(256), 0, stream>>>(nodes, ts, tf, Wq,bq, Wk,bk, Wv,bv, q,k,v);
    k_attn<<<dim3(T*N/4), dim3(256), 0, stream>>>(adj, ts, q,k,v, lng,lnb, mhn);
    k_ff<<<dim3(T*(N/16)), dim3(256), 0, stream>>>(mhn, W1,b1, W2,b2, ff);
    k_gru_pre<<<dim3(T*(N/16)), dim3(256), 0, stream>>>(ff, Wr,br, Wz,bz, Wn,bn, fr,fz,fn);
    hipMemsetAsync(h, 0, (size_t)N*H*sizeof(float), stream);
    for (int t=0; t<T; t++)
        k_gru_step<<<dim3(N/8), dim3(256), 0, stream>>>(h, fr,fz,fn, Wr,Wz,Wn, t);
    k_out<<<dim3(N/16), dim3(256), 0, stream>>>(h, Wout, bout, out);
}

// Round 3
// 326.664 us; speedup vs baseline: 1.5741x; 1.1488x over previous
//
#include <hip/hip_runtime.h>
#include <math.h>

#define T 8
#define N 2048
#define D 64
#define H 128
#define NH 4
#define HD 32
#define TE 16
#define OUT 64
#define E 80
#define CH 128   // score-chunk (online softmax bounds LDS for pathological rows)

__device__ __forceinline__ float gelu_tanh(float x){
    float x3 = x*x*x;
    float t = tanhf(0.7978845608028654f*(x + 0.044715f*x3));
    return 0.5f*x*(1.0f+t);
}
__device__ __forceinline__ float sigmoidf_(float x){ return 1.0f/(1.0f+expf(-x)); }

// ---------------- K1: time-enhanced features + QKV projection (all t) --------
__global__ __launch_bounds__(256) void k_qkv(
    const float* __restrict__ nodes, const float* __restrict__ ts, const float* __restrict__ tf,
    const float* __restrict__ Wq, const float* __restrict__ bq,
    const float* __restrict__ Wk, const float* __restrict__ bk,
    const float* __restrict__ Wv, const float* __restrict__ bv,
    float* __restrict__ q, float* __restrict__ k, float* __restrict__ v)
{
    const int BR = 16;
    __shared__ float A[BR*E];
    int t  = blockIdx.x >> 7;            // 128 blocks per t
    int n0 = (blockIdx.x & 127) * BR;
    int tid = threadIdx.x;
    for (int idx = tid; idx < BR*E; idx += 256){
        int r = idx / E, e = idx - r*E;
        int n = n0 + r;
        float val;
        if (e < D) val = nodes[((size_t)(t*N+n))*D + e];
        else {
            int j = (e - D) & 7;
            float ang = ts[t*N+n] * tf[t*(TE/2)+j];
            val = (e < D+8) ? sinf(ang) : cosf(ang);
        }
        A[idx] = val;
    }
    __syncthreads();
    for (int jj = tid; jj < 3*H; jj += 256){
        int sel = jj >> 7, j = jj & 127;
        const float* W = (sel==0?Wq:(sel==1?Wk:Wv)) + (size_t)t*E*H;
        const float* B = (sel==0?bq:(sel==1?bk:bv)) + t*H;
        float acc[BR];
        float bias = B[j];
        #pragma unroll
        for (int r=0;r<BR;r++) acc[r]=bias;
        for (int e=0;e<E;e+=4){
            float w0=W[(e+0)*H+j], w1=W[(e+1)*H+j], w2=W[(e+2)*H+j], w3=W[(e+3)*H+j];
            #pragma unroll
            for (int r=0;r<BR;r++){
                float4 a = *(const float4*)&A[r*E+e];
                acc[r] += a.x*w0 + a.y*w1 + a.z*w2 + a.w*w3;
            }
        }
        float* outp = (sel==0?q:(sel==1?k:v));
        #pragma unroll
        for (int r=0;r<BR;r++) outp[((size_t)(t*N+n0+r))*H + j] = acc[r];
    }
}

// ---------------- K2: sparse masked attention + LayerNorm --------------------
// One WAVE per row (4 rows/block). Full adjacency row prefetched into
// registers (8x float4) so all HBM loads are in flight together.
__global__ __launch_bounds__(256) void k_attn(
    const float* __restrict__ adj, const float* __restrict__ ts,
    const float* __restrict__ q, const float* __restrict__ k, const float* __restrict__ v,
    const float* __restrict__ ln_g, const float* __restrict__ ln_b,
    float* __restrict__ mhn)
{
    __shared__ unsigned short nb_s[4][N];     // 16 KB
    __shared__ float sc_s[4][CH][NH];         // 8 KB
    __shared__ float qrow_s[4][H];            // 2 KB

    int wid  = threadIdx.x >> 6;
    int lane = threadIdx.x & 63;
    int row  = blockIdx.x*4 + wid;            // 0 .. T*N-1
    int t = row >> 11, n = row & 2047;
    size_t rowbase = (size_t)row;
    const float4* arow4 = (const float4*)(adj + rowbase*(size_t)N);
    float tsn = ts[row];

    // issue the entire adjacency row up front: 8 KB/wave in flight
    float4 a4[8];
    #pragma unroll
    for (int it=0; it<8; it++) a4[it] = arow4[it*64 + lane];

    qrow_s[wid][lane]    = q[rowbase*H + lane];
    qrow_s[wid][lane+64] = q[rowbase*H + lane + 64];
    __builtin_amdgcn_wave_barrier();

    // ---- wave-local neighbor compaction (ordered, deterministic) ----
    int cnt = 0;
    unsigned long long lt = (1ull<<lane)-1ull;
    #pragma unroll
    for (int it = 0; it < 8; it++){
        int m0 = it*256 + lane*4;
        bool f0 = (a4[it].x>0.f) || (m0   == n);
        bool f1 = (a4[it].y>0.f) || (m0+1 == n);
        bool f2 = (a4[it].z>0.f) || (m0+2 == n);
        bool f3 = (a4[it].w>0.f) || (m0+3 == n);
        unsigned long long b0=__ballot(f0), b1=__ballot(f1), b2=__ballot(f2), b3=__ballot(f3);
        int before = __popcll(b0&lt)+__popcll(b1&lt)+__popcll(b2&lt)+__popcll(b3&lt);
        int pos = cnt + before;
        if (f0) nb_s[wid][pos] = (unsigned short)(m0  );  pos += f0;
        if (f1) nb_s[wid][pos] = (unsigned short)(m0+1);  pos += f1;
        if (f2) nb_s[wid][pos] = (unsigned short)(m0+2);  pos += f2;
        if (f3) nb_s[wid][pos] = (unsigned short)(m0+3);  pos += f3;
        cnt += __popcll(b0)+__popcll(b1)+__popcll(b2)+__popcll(b3);
    }
    __builtin_amdgcn_wave_barrier();

    // ---- online softmax + PV over chunks ----
    const float inv_sqrt_hd = 0.17677669529663687f;
    int hh16 = lane >> 4;          // head this lane serves in softmax (16 lanes/head)
    int l16  = lane & 15;
    int ha0  = lane >> 5;          // head of output dim j0=lane     (0/1)
    int ha1  = ha0 + 2;            // head of output dim j1=lane+64  (2/3)
    float m_run = -3.402823466e38f, s_run = 0.f;
    float acc0 = 0.f, acc1 = 0.f;

    for (int cb = 0; cb < cnt; cb += CH){
        int cc = min(CH, cnt - cb);
        // scores for (neighbor, head)
        for (int i = lane; i < cc*NH; i += 64){
            int li = i >> 2, hh = i & 3;
            int m = nb_s[wid][cb + li];
            const float4* kp = (const float4*)(k + ((size_t)t*N + m)*H + hh*HD);
            const float4* qp = (const float4*)&qrow_s[wid][hh*HD];
            float dot = 0.f;
            #pragma unroll
            for (int u=0;u<8;u++){
                float4 a = qp[u], b = kp[u];
                dot += a.x*b.x + a.y*b.y + a.z*b.z + a.w*b.w;
            }
            float dt = fabsf(tsn - ts[t*N + m]);
            sc_s[wid][li][hh] = dot * inv_sqrt_hd * expf(-dt*0.1f);
        }
        __builtin_amdgcn_wave_barrier();
        // chunk max per head
        float mx = -3.402823466e38f;
        for (int i = l16; i < cc; i += 16) mx = fmaxf(mx, sc_s[wid][i][hh16]);
        #pragma unroll
        for (int off=8; off; off>>=1) mx = fmaxf(mx, __shfl_xor(mx, off, 16));
        float m_new = fmaxf(m_run, mx);
        float scale = expf(m_run - m_new);     // first chunk: exp(-inf)=0
        float sum = 0.f;
        for (int i = l16; i < cc; i += 16){
            float p = expf(sc_s[wid][i][hh16] - m_new);
            sc_s[wid][i][hh16] = p;
            sum += p;
        }
        #pragma unroll
        for (int off=8; off; off>>=1) sum += __shfl_xor(sum, off, 16);
        s_run = s_run*scale + sum;
        m_run = m_new;
        float sca0 = __shfl(scale, ha0*16, 64);
        float sca1 = __shfl(scale, ha1*16, 64);
        acc0 *= sca0; acc1 *= sca1;
        __builtin_amdgcn_wave_barrier();
        // PV: lane accumulates output dims (lane) and (lane+64)
        #pragma unroll 4
        for (int i = 0; i < cc; i++){
            int m = nb_s[wid][cb + i];
            const float* vp = v + ((size_t)t*N + m)*H;
            float p0 = sc_s[wid][i][ha0];
            float p1 = sc_s[wid][i][ha1];
            acc0 += p0 * vp[lane];
            acc1 += p1 * vp[lane+64];
        }
        __builtin_amdgcn_wave_barrier();
    }

    float s0 = __shfl(s_run, ha0*16, 64);
    float s1 = __shfl(s_run, ha1*16, 64);
    float mh0 = acc0 / s0, mh1 = acc1 / s1;

    // fused LayerNorm (eps=1e-6), all in-wave
    float sum = mh0 + mh1;
    #pragma unroll
    for (int off=32; off; off>>=1) sum += __shfl_xor(sum, off);
    float mu = sum * (1.f/128.f);
    float d0 = mh0 - mu, d1 = mh1 - mu;
    float vv = d0*d0 + d1*d1;
    #pragma unroll
    for (int off=32; off; off>>=1) vv += __shfl_xor(vv, off);
    float rs = rsqrtf(vv*(1.f/128.f) + 1e-6f);
    mhn[rowbase*H + lane]      = d0*rs*ln_g[t*H+lane]      + ln_b[t*H+lane];
    mhn[rowbase*H + lane+64]   = d1*rs*ln_g[t*H+lane+64]   + ln_b[t*H+lane+64];
}

// ---------------- K3: GELU-MLP 128 -> 256 -> 128 (all t) ---------------------
__global__ __launch_bounds__(256) void k_ff(
    const float* __restrict__ mhn,
    const float* __restrict__ W1, const float* __restrict__ b1,
    const float* __restrict__ W2, const float* __restrict__ b2,
    float* __restrict__ ff)
{
    const int BR = 16;
    __shared__ float A[BR*H];
    __shared__ float U[BR*2*H];
    int t  = blockIdx.x >> 7;
    int n0 = (blockIdx.x & 127) * BR;
    int tid = threadIdx.x;
    for (int idx = tid; idx < BR*H; idx += 256)
        A[idx] = mhn[((size_t)(t*N+n0))*H + idx];
    __syncthreads();
    {
        int j = tid;
        const float* W = W1 + (size_t)t*H*2*H;
        float acc[BR];
        float bias = b1[t*2*H + j];
        #pragma unroll
        for (int r=0;r<BR;r++) acc[r]=bias;
        for (int e=0;e<H;e+=4){
            float w0=W[(e+0)*256+j],w1=W[(e+1)*256+j],w2=W[(e+2)*256+j],w3=W[(e+3)*256+j];
            #pragma unroll
            for (int r=0;r<BR;r++){
                float4 a = *(const float4*)&A[r*H+e];
                acc[r] += a.x*w0+a.y*w1+a.z*w2+a.w*w3;
            }
        }
        #pragma unroll
        for (int r=0;r<BR;r++) U[r*256+j] = gelu_tanh(acc[r]);
    }
    __syncthreads();
    {
        int j = tid & 127, rg = tid >> 7;   // 2 groups x 8 rows
        const float* W = W2 + (size_t)t*2*H*H;
        float acc[8];
        float bias = b2[t*H+j];
        #pragma unroll
        for (int rr=0;rr<8;rr++) acc[rr]=bias;
        for (int e=0;e<256;e+=4){
            float w0=W[(e+0)*H+j],w1=W[(e+1)*H+j],w2=W[(e+2)*H+j],w3=W[(e+3)*H+j];
            #pragma unroll
            for (int rr=0;rr<8;rr++){
                int r = rg*8+rr;
                float4 a = *(const float4*)&U[r*256+e];
                acc[rr] += a.x*w0+a.y*w1+a.z*w2+a.w*w3;
            }
        }
        #pragma unroll
        for (int rr=0;rr<8;rr++) ff[((size_t)(t*N+n0+rg*8+rr))*H + j] = acc[rr];
    }
}

// ---------------- K4: GRU bottom-half projections ff@W_bot + b (all t) -------
__global__ __launch_bounds__(256) void k_gru_pre(
    const float* __restrict__ ff,
    const float* __restrict__ Wr, const float* __restrict__ br,
    const float* __restrict__ Wz, const float* __restrict__ bz,
    const float* __restrict__ Wn, const float* __restrict__ bn,
    float* __restrict__ fr, float* __restrict__ fz, float* __restrict__ fn)
{
    const int BR = 16;
    __shared__ float A[BR*H];
    int t  = blockIdx.x >> 7;
    int n0 = (blockIdx.x & 127) * BR;
    int tid = threadIdx.x;
    for (int idx = tid; idx < BR*H; idx += 256)
        A[idx] = ff[((size_t)(t*N+n0))*H + idx];
    __syncthreads();
    for (int jj = tid; jj < 3*H; jj += 256){
        int sel = jj >> 7, j = jj & 127;
        const float* W = (sel==0?Wr:(sel==1?Wz:Wn)) + (size_t)t*2*H*H + (size_t)H*H; // bottom rows
        const float* B = (sel==0?br:(sel==1?bz:bn)) + t*H;
        float* outp = (sel==0?fr:(sel==1?fz:fn));
        float acc[BR];
        float bias = B[j];
        #pragma unroll
        for (int r=0;r<BR;r++) acc[r]=bias;
        for (int e=0;e<H;e+=4){
            float w0=W[(e+0)*H+j],w1=W[(e+1)*H+j],w2=W[(e+2)*H+j],w3=W[(e+3)*H+j];
            #pragma unroll
            for (int r=0;r<BR;r++){
                float4 a = *(const float4*)&A[r*H+e];
                acc[r]+=a.x*w0+a.y*w1+a.z*w2+a.w*w3;
            }
        }
        #pragma unroll
        for (int r=0;r<BR;r++) outp[((size_t)(t*N+n0+r))*H + j] = acc[r];
    }
}

// ---------------- K5: GRU sequential step (in-place h update) ----------------
// BR=4 -> 512 blocks (2/CU): halves per-wave serial FMA chains vs BR=8.
__global__ __launch_bounds__(256) void k_gru_step(
    float* h,
    const float* __restrict__ fr, const float* __restrict__ fz, const float* __restrict__ fn,
    const float* __restrict__ Wr, const float* __restrict__ Wz, const float* __restrict__ Wn,
    int t)
{
    const int BR = 4;
    __shared__ float Hs[BR*H], Rl[BR*H], Zl[BR*H], RH[BR*H];
    int n0 = blockIdx.x * BR;
    int tid = threadIdx.x;
    for (int idx = tid; idx < BR*H; idx += 256)
        Hs[idx] = h[(size_t)n0*H + idx];
    __syncthreads();
    {
        int sel = tid >> 7, j = tid & 127;
        const float* W = (sel==0?Wr:Wz) + (size_t)t*2*H*H;   // top rows 0..127
        const float* P = (sel==0?fr:fz);
        float acc[BR];
        #pragma unroll
        for (int r=0;r<BR;r++) acc[r] = P[((size_t)(t*N+n0+r))*H + j];
        for (int e=0;e<H;e+=4){
            float w0=W[(e+0)*H+j],w1=W[(e+1)*H+j],w2=W[(e+2)*H+j],w3=W[(e+3)*H+j];
            #pragma unroll
            for (int r=0;r<BR;r++){
                float4 a = *(const float4*)&Hs[r*H+e];
                acc[r]+=a.x*w0+a.y*w1+a.z*w2+a.w*w3;
            }
        }
        float* Dst = (sel==0?Rl:Zl);
        #pragma unroll
        for (int r=0;r<BR;r++) Dst[r*H+j] = sigmoidf_(acc[r]);
    }
    __syncthreads();
    for (int idx = tid; idx < BR*H; idx += 256) RH[idx] = Rl[idx]*Hs[idx];
    __syncthreads();
    {
        int rg = tid >> 7, j = tid & 127;   // 2 groups x 2 rows
        const float* W = Wn + (size_t)t*2*H*H;
        float acc[2];
        #pragma unroll
        for (int rr=0;rr<2;rr++) acc[rr] = fn[((size_t)(t*N+n0+rg*2+rr))*H + j];
        for (int e=0;e<H;e+=4){
            float w0=W[(e+0)*H+j],w1=W[(e+1)*H+j],w2=W[(e+2)*H+j],w3=W[(e+3)*H+j];
            #pragma unroll
            for (int rr=0;rr<2;rr++){
                int r = rg*2+rr;
                float4 a = *(const float4*)&RH[r*H+e];
                acc[rr]+=a.x*w0+a.y*w1+a.z*w2+a.w*w3;
            }
        }
        #pragma unroll
        for (int rr=0;rr<2;rr++){
            int r = rg*2+rr;
            float nv = tanhf(acc[rr]);
            float zz = Zl[r*H+j];
            h[(size_t)(n0+r)*H + j] = (1.f-zz)*nv + zz*Hs[r*H+j];
        }
    }
}

// ---------------- K6: final projection h @ Wout + bout ----------------------
__global__ __launch_bounds__(256) void k_out(
    const float* __restrict__ h, const float* __restrict__ Wout, const float* __restrict__ bout,
    float* __restrict__ out)
{
    const int BR = 16;
    __shared__ float Hs[BR*H];
    int n0 = blockIdx.x * BR;
    int tid = threadIdx.x;
    for (int idx=tid; idx<BR*H; idx+=256) Hs[idx] = h[(size_t)n0*H+idx];
    __syncthreads();
    int j = tid & 63, rg = tid >> 6;
    float acc[4];
    float bias = bout[j];
    #pragma unroll
    for (int rr=0;rr<4;rr++) acc[rr]=bias;
    for (int e=0;e<H;e+=4){
        float w0=Wout[(e+0)*OUT+j],w1=Wout[(e+1)*OUT+j],w2=Wout[(e+2)*OUT+j],w3=Wout[(e+3)*OUT+j];
        #pragma unroll
        for (int rr=0;rr<4;rr++){
            int r = rg*4+rr;
            float4 a = *(const float4*)&Hs[r*H+e];
            acc[rr]+=a.x*w0+a.y*w1+a.z*w2+a.w*w3;
        }
    }
    #pragma unroll
    for (int rr=0;rr<4;rr++) out[(size_t)(n0+rg*4+rr)*OUT + j] = acc[rr];
}

extern "C" void kernel_launch(void* const* d_in, const int* in_sizes, int n_in,
                              void* d_out, int out_size, void* d_ws, size_t ws_size,
                              hipStream_t stream)
{
    const float* nodes = (const float*)d_in[0];
    const float* adj   = (const float*)d_in[1];
    const float* ts    = (const float*)d_in[2];
    // d_in[3] = edge_sequence (unused)
    const float* tf    = (const float*)d_in[4];
    const float* Wq = (const float*)d_in[5];  const float* bq = (const float*)d_in[6];
    const float* Wk = (const float*)d_in[7];  const float* bk = (const float*)d_in[8];
    const float* Wv = (const float*)d_in[9];  const float* bv = (const float*)d_in[10];
    const float* lng = (const float*)d_in[11]; const float* lnb = (const float*)d_in[12];
    const float* W1 = (const float*)d_in[13]; const float* b1 = (const float*)d_in[14];
    const float* W2 = (const float*)d_in[15]; const float* b2 = (const float*)d_in[16];
    const float* Wr = (const float*)d_in[17]; const float* br = (const float*)d_in[18];
    const float* Wz = (const float*)d_in[19]; const float* bz = (const float*)d_in[20];
    const float* Wn = (const float*)d_in[21]; const float* bn = (const float*)d_in[22];
    const float* Wout = (const float*)d_in[23]; const float* bout = (const float*)d_in[24];
    float* out = (float*)d_out;

    const size_t TNH = (size_t)T*N*H;
    float* ws  = (float*)d_ws;
    float* q   = ws;
    float* k   = q  + TNH;
    float* v   = k  + TNH;
    float* mhn = v  + TNH;
    float* ff  = mhn+ TNH;
    float* fr  = ff + TNH;
    float* fz  = fr + TNH;
    float* fn  = fz + TNH;
    float* h   = fn + TNH;     // N*H

    k_qkv<<<dim3(T*(N/16)), dim3(256), 0, stream>>>(nodes, ts, tf, Wq,bq, Wk,bk, Wv,bv, q,k,v);
    k_attn<<<dim3(T*N/4), dim3(256), 0, stream>>>(adj, ts, q,k,v, lng,lnb, mhn);
    k_ff<<<dim3(T*(N/16)), dim3(256), 0, stream>>>(mhn, W1,b1, W2,b2, ff);
    k_gru_pre<<<dim3(T*(N/16)), dim3(256), 0, stream>>>(ff, Wr,br, Wz,bz, Wn,bn, fr,fz,fn);
    hipMemsetAsync(h, 0, (size_t)N*H*sizeof(float), stream);
    for (int t=0; t<T; t++)
        k_gru_step<<<dim3(N/4), dim3(256), 0, stream>>>(h, fr,fz,fn, Wr,Wz,Wn, t);
    k_out<<<dim3(N/16), dim3(256), 0, stream>>>(h, Wout, bout, out);
}